// Round 10
// baseline (503.303 us; speedup 1.0000x reference)
//
#include <hip/hip_runtime.h>
#include <stdint.h>
#include <math.h>

typedef short short8 __attribute__((ext_vector_type(8)));
typedef float f32x4 __attribute__((ext_vector_type(4)));

// Problem constants
#define S_LEN   2048
#define DMODEL  2048
#define NHEADS  16
#define HDIM    128
#define NBATCH  2
#define BHTOT   32      // NBATCH*NHEADS
#define MROWS   4096    // NBATCH*S_LEN

// Workspace byte offsets
#define XB_OFF   ((size_t)0)          // x bf16; reused as attn-output O
#define WQ_OFF   ((size_t)16777216)   // Wq bf16; reused for Wo bf16 (fallback path)
#define WK_OFF   ((size_t)25165824)
#define WV_OFF   ((size_t)33554432)
#define Q_OFF    ((size_t)41943040)   // (bh,s,d) bf16
#define K_OFF    ((size_t)58720256)   // (bh,s,d) bf16
#define VT_OFF   ((size_t)75497472)   // (bh,d,s) bf16 (V pre-transposed)
#define COS_OFF  ((size_t)92274688)   // 2048*64 f32
#define SIN_OFF  ((size_t)92798976)   // 2048*64 f32
#define WO_OFF   ((size_t)93323264)   // dedicated Wo bf16 slot (if ws_size permits)
#define WS_NEED  (WO_OFF + (size_t)8388608)

__device__ __forceinline__ unsigned short f2bf(float f) {
  unsigned int u = __float_as_uint(f);
  unsigned int r = (u + 0x7FFFu + ((u >> 16) & 1u)) >> 16;  // RTNE
  return (unsigned short)r;
}
__device__ __forceinline__ float bf2f(unsigned short b) {
  return __uint_as_float(((unsigned int)b) << 16);
}

// async global->LDS, 16B per lane; LDS dest = wave-uniform base + lane*16
__device__ __forceinline__ void gl_lds16(const unsigned short* g, unsigned short* l) {
  __builtin_amdgcn_global_load_lds(
      (const __attribute__((address_space(1))) unsigned int*)(g),
      (__attribute__((address_space(3))) unsigned int*)(l),
      16, 0, 0);
}

// ---------------- fp32 -> bf16 convert (fallback for Wo) ----------------
__global__ __launch_bounds__(256) void k_cvt(const float* __restrict__ src,
                                             unsigned short* __restrict__ dst, int n4) {
  int i = blockIdx.x * 256 + threadIdx.x;
  if (i >= n4) return;
  float4 v = ((const float4*)src)[i];
  ushort4 o;
  o.x = f2bf(v.x); o.y = f2bf(v.y); o.z = f2bf(v.z); o.w = f2bf(v.w);
  ((ushort4*)dst)[i] = o;
}

// ---------------- merged prep: x->bf16, Wq/Wk/Wv(/Wo)->bf16, RoPE table ----------------
__global__ __launch_bounds__(256) void k_prep(
    const float* __restrict__ x, const float* __restrict__ Wq,
    const float* __restrict__ Wk, const float* __restrict__ Wv,
    const float* __restrict__ Wo,
    unsigned short* __restrict__ xb, unsigned short* __restrict__ wqb,
    unsigned short* __restrict__ wkb, unsigned short* __restrict__ wvb,
    unsigned short* __restrict__ wob,   // null if no dedicated slot
    float* __restrict__ ct, float* __restrict__ st) {
  int i = blockIdx.x * 256 + threadIdx.x;
  if (i < 6291456) {                       // float4 converts: x (2^21) + 4 W (2^20 each)
    const float* s; unsigned short* d; int off;
    if (i < 2097152) { s = x; d = xb; off = i; }
    else {
      int j = i - 2097152, sel = j >> 20;
      off = j & 1048575;
      if (sel == 3) {
        if (!wob) return;                  // fallback: separate k_cvt handles Wo
        s = Wo; d = wob;
      } else {
        s = (sel == 0) ? Wq : (sel == 1 ? Wk : Wv);
        d = (sel == 0) ? wqb : (sel == 1 ? wkb : wvb);
      }
    }
    float4 v = ((const float4*)s)[off];
    ushort4 o;
    o.x = f2bf(v.x); o.y = f2bf(v.y); o.z = f2bf(v.z); o.w = f2bf(v.w);
    ((ushort4*)d)[off] = o;
  } else {
    int j = i - 6291456;                   // 2048*64 rope table entries
    if (j < S_LEN * 64) {
      int s = j >> 6, jj = j & 63;
      float inv = expf(-(float)(2 * jj) * (9.210340371976184f / 128.0f));
      float ang = (float)s * inv;
      ct[j] = cosf(ang);
      st[j] = sinf(ang);
    }
  }
}

// ======== shared GEMM core macros (A direct-to-reg, B via gl_lds dbuf) ========
// A-frag names: <S>0..3 = kk=0 (m=0..3), <S>4..7 = kk=1 (m=0..3)
#define LOAD_A(S, kn)                                  \
    S##0 = *(const short8*)(arow0 + (kn));             \
    S##1 = *(const short8*)(arow1 + (kn));             \
    S##2 = *(const short8*)(arow2 + (kn));             \
    S##3 = *(const short8*)(arow3 + (kn));             \
    S##4 = *(const short8*)(arow0 + (kn) + 32);        \
    S##5 = *(const short8*)(arow1 + (kn) + 32);        \
    S##6 = *(const short8*)(arow2 + (kn) + 32);        \
    S##7 = *(const short8*)(arow3 + (kn) + 32);

#define STAGE_B(BP, kn, dst)                                                            \
    gl_lds16((BP) + (size_t)(nb0 + gr     ) * DMODEL + (kn) + gc, (dst) + (wid*32     )*64); \
    gl_lds16((BP) + (size_t)(nb0 + gr +  8) * DMODEL + (kn) + gc, (dst) + (wid*32 +  8)*64); \
    gl_lds16((BP) + (size_t)(nb0 + gr + 16) * DMODEL + (kn) + gc, (dst) + (wid*32 + 16)*64); \
    gl_lds16((BP) + (size_t)(nb0 + gr + 24) * DMODEL + (kn) + gc, (dst) + (wid*32 + 24)*64);

#define COMPUTE_STEP(S)                                                                  \
    { const unsigned short* Bc = SMEM + cur * 8192;                                      \
      short8 b0, b1, b2, b3;                                                             \
      b0 = *(const short8*)&Bc[(wc*64 +  0 + lq)*64 + ((lk*8) ^ sw)];                    \
      b1 = *(const short8*)&Bc[(wc*64 + 16 + lq)*64 + ((lk*8) ^ sw)];                    \
      b2 = *(const short8*)&Bc[(wc*64 + 32 + lq)*64 + ((lk*8) ^ sw)];                    \
      b3 = *(const short8*)&Bc[(wc*64 + 48 + lq)*64 + ((lk*8) ^ sw)];                    \
      acc[0][0] = __builtin_amdgcn_mfma_f32_16x16x32_bf16(S##0, b0, acc[0][0], 0,0,0);   \
      acc[1][0] = __builtin_amdgcn_mfma_f32_16x16x32_bf16(S##1, b0, acc[1][0], 0,0,0);   \
      acc[2][0] = __builtin_amdgcn_mfma_f32_16x16x32_bf16(S##2, b0, acc[2][0], 0,0,0);   \
      acc[3][0] = __builtin_amdgcn_mfma_f32_16x16x32_bf16(S##3, b0, acc[3][0], 0,0,0);   \
      acc[0][1] = __builtin_amdgcn_mfma_f32_16x16x32_bf16(S##0, b1, acc[0][1], 0,0,0);   \
      acc[1][1] = __builtin_amdgcn_mfma_f32_16x16x32_bf16(S##1, b1, acc[1][1], 0,0,0);   \
      acc[2][1] = __builtin_amdgcn_mfma_f32_16x16x32_bf16(S##2, b1, acc[2][1], 0,0,0);   \
      acc[3][1] = __builtin_amdgcn_mfma_f32_16x16x32_bf16(S##3, b1, acc[3][1], 0,0,0);   \
      acc[0][2] = __builtin_amdgcn_mfma_f32_16x16x32_bf16(S##0, b2, acc[0][2], 0,0,0);   \
      acc[1][2] = __builtin_amdgcn_mfma_f32_16x16x32_bf16(S##1, b2, acc[1][2], 0,0,0);   \
      acc[2][2] = __builtin_amdgcn_mfma_f32_16x16x32_bf16(S##2, b2, acc[2][2], 0,0,0);   \
      acc[3][2] = __builtin_amdgcn_mfma_f32_16x16x32_bf16(S##3, b2, acc[3][2], 0,0,0);   \
      acc[0][3] = __builtin_amdgcn_mfma_f32_16x16x32_bf16(S##0, b3, acc[0][3], 0,0,0);   \
      acc[1][3] = __builtin_amdgcn_mfma_f32_16x16x32_bf16(S##1, b3, acc[1][3], 0,0,0);   \
      acc[2][3] = __builtin_amdgcn_mfma_f32_16x16x32_bf16(S##2, b3, acc[2][3], 0,0,0);   \
      acc[3][3] = __builtin_amdgcn_mfma_f32_16x16x32_bf16(S##3, b3, acc[3][3], 0,0,0);   \
      b0 = *(const short8*)&Bc[(wc*64 +  0 + lq)*64 + ((32 + lk*8) ^ sw)];               \
      b1 = *(const short8*)&Bc[(wc*64 + 16 + lq)*64 + ((32 + lk*8) ^ sw)];               \
      b2 = *(const short8*)&Bc[(wc*64 + 32 + lq)*64 + ((32 + lk*8) ^ sw)];               \
      b3 = *(const short8*)&Bc[(wc*64 + 48 + lq)*64 + ((32 + lk*8) ^ sw)];               \
      acc[0][0] = __builtin_amdgcn_mfma_f32_16x16x32_bf16(S##4, b0, acc[0][0], 0,0,0);   \
      acc[1][0] = __builtin_amdgcn_mfma_f32_16x16x32_bf16(S##5, b0, acc[1][0], 0,0,0);   \
      acc[2][0] = __builtin_amdgcn_mfma_f32_16x16x32_bf16(S##6, b0, acc[2][0], 0,0,0);   \
      acc[3][0] = __builtin_amdgcn_mfma_f32_16x16x32_bf16(S##7, b0, acc[3][0], 0,0,0);   \
      acc[0][1] = __builtin_amdgcn_mfma_f32_16x16x32_bf16(S##4, b1, acc[0][1], 0,0,0);   \
      acc[1][1] = __builtin_amdgcn_mfma_f32_16x16x32_bf16(S##5, b1, acc[1][1], 0,0,0);   \
      acc[2][1] = __builtin_amdgcn_mfma_f32_16x16x32_bf16(S##6, b1, acc[2][1], 0,0,0);   \
      acc[3][1] = __builtin_amdgcn_mfma_f32_16x16x32_bf16(S##7, b1, acc[3][1], 0,0,0);   \
      acc[0][2] = __builtin_amdgcn_mfma_f32_16x16x32_bf16(S##4, b2, acc[0][2], 0,0,0);   \
      acc[1][2] = __builtin_amdgcn_mfma_f32_16x16x32_bf16(S##5, b2, acc[1][2], 0,0,0);   \
      acc[2][2] = __builtin_amdgcn_mfma_f32_16x16x32_bf16(S##6, b2, acc[2][2], 0,0,0);   \
      acc[3][2] = __builtin_amdgcn_mfma_f32_16x16x32_bf16(S##7, b2, acc[3][2], 0,0,0);   \
      acc[0][3] = __builtin_amdgcn_mfma_f32_16x16x32_bf16(S##4, b3, acc[0][3], 0,0,0);   \
      acc[1][3] = __builtin_amdgcn_mfma_f32_16x16x32_bf16(S##5, b3, acc[1][3], 0,0,0);   \
      acc[2][3] = __builtin_amdgcn_mfma_f32_16x16x32_bf16(S##6, b3, acc[2][3], 0,0,0);   \
      acc[3][3] = __builtin_amdgcn_mfma_f32_16x16x32_bf16(S##7, b3, acc[3][3], 0,0,0); }

#define GEMM_PRE_BODY(APTR, BPTR)                                                 \
  int tid = threadIdx.x, lane = tid & 63, wid = tid >> 6;                         \
  int wr = wid >> 1, wc = wid & 1;                                                \
  int lq = lane & 15, lk = lane >> 4;                                             \
  int gr = wid * 32 + (lane >> 3);                                                \
  int gc = ((lane & 7) * 8) ^ ((lane >> 3) << 3);                                 \
  int sw = (lq & 7) << 3;                                                         \
  const unsigned short* arow0 = (APTR) + (size_t)(m0 + wr*64 +  0 + lq) * DMODEL + lk*8; \
  const unsigned short* arow1 = (APTR) + (size_t)(m0 + wr*64 + 16 + lq) * DMODEL + lk*8; \
  const unsigned short* arow2 = (APTR) + (size_t)(m0 + wr*64 + 32 + lq) * DMODEL + lk*8; \
  const unsigned short* arow3 = (APTR) + (size_t)(m0 + wr*64 + 48 + lq) * DMODEL + lk*8; \
  f32x4 acc[4][4];                                                                \
  _Pragma("unroll")                                                               \
  for (int m = 0; m < 4; m++)                                                     \
    _Pragma("unroll")                                                             \
    for (int n = 0; n < 4; n++) { acc[m][n][0]=0.f; acc[m][n][1]=0.f; acc[m][n][2]=0.f; acc[m][n][3]=0.f; } \
  short8 Aa0,Aa1,Aa2,Aa3,Aa4,Aa5,Aa6,Aa7;                                         \
  short8 Ab0,Ab1,Ab2,Ab3,Ab4,Ab5,Ab6,Ab7;                                         \
  /* prologue: B tile0 -> buf0; A frags tile0 -> Aa */                            \
  STAGE_B(BPTR, 0, SMEM)                                                          \
  LOAD_A(Aa, 0)                                                                   \
  __syncthreads();                                                                \
  int cur = 0;                                                                    \
  for (int k0 = 0; k0 < DMODEL; k0 += 128) {                                      \
    if (k0 + 64 < DMODEL) {                                                       \
      unsigned short* Bn = SMEM + (cur ^ 1) * 8192;                               \
      STAGE_B(BPTR, k0 + 64, Bn)                                                  \
      LOAD_A(Ab, k0 + 64)                                                         \
    }                                                                             \
    COMPUTE_STEP(Aa)                                                              \
    __syncthreads(); cur ^= 1;                                                    \
    if (k0 + 128 < DMODEL) {                                                      \
      unsigned short* Bn = SMEM + (cur ^ 1) * 8192;                               \
      STAGE_B(BPTR, k0 + 128, Bn)                                                 \
      LOAD_A(Aa, k0 + 128)                                                        \
    }                                                                             \
    COMPUTE_STEP(Ab)                                                              \
    __syncthreads(); cur ^= 1;                                                    \
  }

// ---------------- fused QKV projection GEMM + RoPE + transpose epilogue ----------------
// A (xb) direct-to-reg prefetched; B via 2-phase gl_lds dbuf (sync structure unchanged).
#define CP 136
__global__ __launch_bounds__(256) void k_gemm_qkv(
    const unsigned short* __restrict__ xb,
    const unsigned short* __restrict__ wqb, const unsigned short* __restrict__ wkb,
    const unsigned short* __restrict__ wvb,
    const float* __restrict__ bq, const float* __restrict__ bk, const float* __restrict__ bv,
    const float* __restrict__ ct, const float* __restrict__ st,
    unsigned short* __restrict__ qr, unsigned short* __restrict__ kr,
    unsigned short* __restrict__ vt) {
  __shared__ unsigned short SMEM[17408];   // B dbuf [0,16384); epilogue reuses [0,17408)
  int m0 = blockIdx.x * 128;
  int n0g = blockIdx.y * 128;              // 0..6143
  int wsel = n0g >> 11;                    // 0=Q 1=K 2=V
  int nb0 = n0g & (DMODEL - 1);
  const unsigned short* W = (wsel == 0) ? wqb : (wsel == 1 ? wkb : wvb);
  const float* bias = (wsel == 0) ? bq : (wsel == 1 ? bk : bv);

  GEMM_PRE_BODY(xb, W)

  // ---- epilogue: bias (+RoPE for Q/K) -> SMEM in target layout -> coalesced store
  int h = nb0 >> 7, b = m0 >> 11, s0 = m0 & (S_LEN - 1);
  float bi[4];
#pragma unroll
  for (int n = 0; n < 4; n++) bi[n] = bias[nb0 + wc * 64 + n * 16 + lq];

  if (wsel < 2) {
    float qs = (wsel == 0) ? 0.08838834764831843f : 1.0f;
    if (wc == 0) {
#pragma unroll
      for (int m = 0; m < 4; m++) {
        int sl = wr * 64 + m * 16 + lk * 4;
#pragma unroll
        for (int r = 0; r < 4; r++) {
          int s = (s0 + sl + r);
          const float* cb = ct + s * 64;
          const float* sb = st + s * 64;
#pragma unroll
          for (int n = 0; n < 2; n++) {
            int fq = n * 16 + lq;
            float x1 = acc[m][n][r] + bi[n];
            float x2 = acc[m][n + 2][r] + bi[n + 2];
            SMEM[(sl + r) * CP + fq]      = f2bf((x1 * cb[fq]      - x2 * sb[fq])      * qs);
            SMEM[(sl + r) * CP + fq + 32] = f2bf((x2 * cb[fq + 32] + x1 * sb[fq + 32]) * qs);
          }
        }
      }
    } else {
#pragma unroll
      for (int m = 0; m < 4; m++) {
        int sl = wr * 64 + m * 16 + lk * 4;
#pragma unroll
        for (int n = 0; n < 4; n++) {
          int fq = 64 + n * 16 + lq;
#pragma unroll
          for (int r = 0; r < 4; r++)
            SMEM[(sl + r) * CP + fq] = f2bf((acc[m][n][r] + bi[n]) * qs);
        }
      }
    }
    __syncthreads();
    int row = tid >> 1, hf2 = tid & 1;
    unsigned short* dstb = (wsel == 0 ? qr : kr) +
        ((size_t)(b * NHEADS + h) * S_LEN + s0 + row) * HDIM + hf2 * 64;
    const unsigned short* srcb = &SMEM[row * CP + hf2 * 64];
#pragma unroll
    for (int j = 0; j < 8; j++)
      *(short8*)(dstb + j * 8) = *(const short8*)(srcb + j * 8);
  } else {
#pragma unroll
    for (int m = 0; m < 4; m++) {
      int sl = wr * 64 + m * 16 + lk * 4;
#pragma unroll
      for (int n = 0; n < 4; n++) {
        int fq = wc * 64 + n * 16 + lq;
#pragma unroll
        for (int r = 0; r < 4; r++)
          SMEM[fq * CP + sl + r] = f2bf(acc[m][n][r] + bi[n]);
      }
    }
    __syncthreads();
    int row = tid >> 1, hf2 = tid & 1;
    unsigned short* dstb = vt +
        ((size_t)(b * NHEADS + h) * HDIM + row) * S_LEN + s0 + hf2 * 64;
    const unsigned short* srcb = &SMEM[row * CP + hf2 * 64];
#pragma unroll
    for (int j = 0; j < 8; j++)
      *(short8*)(dstb + j * 8) = *(const short8*)(srcb + j * 8);
  }
}

// ---------------- output projection GEMM (A direct-to-reg, fp32 out) ----------------
__global__ __launch_bounds__(256) void k_gemm_out(
    const unsigned short* __restrict__ ob, const unsigned short* __restrict__ wob,
    const float* __restrict__ bo, float* __restrict__ out) {
  __shared__ unsigned short SMEM[16384];   // B dbuf only (32 KB)
  int m0 = blockIdx.x * 128;
  int nb0 = blockIdx.y * 128;

  GEMM_PRE_BODY(ob, wob)

#pragma unroll
  for (int n = 0; n < 4; n++) {
    int el = nb0 + wc * 64 + n * 16 + lq;
    float bi = bo[el];
#pragma unroll
    for (int m = 0; m < 4; m++) {
      int row = m0 + wr * 64 + m * 16 + lk * 4;
#pragma unroll
      for (int r = 0; r < 4; r++)
        out[(size_t)(row + r) * DMODEL + el] = acc[m][n][r] + bi;
    }
  }
}

// ---------------- attn per-tile softmax (defer-max, per-lane partial sums) ----------------
__device__ __forceinline__ void attn_sm_pv(
    f32x4* sacc, f32x4* acco, float* rm, float* rs,
    unsigned short (*Psw)[72], const unsigned short* V0,
    int lq, int lk, int rsw) {
  float mx4[4];
  int need = 0;
#pragma unroll
  for (int r = 0; r < 4; r++) {
    float mx = fmaxf(fmaxf(sacc[0][r], sacc[1][r]), fmaxf(sacc[2][r], sacc[3][r]));
    mx = fmaxf(mx, __shfl_xor(mx, 1, 64));
    mx = fmaxf(mx, __shfl_xor(mx, 2, 64));
    mx = fmaxf(mx, __shfl_xor(mx, 4, 64));
    mx = fmaxf(mx, __shfl_xor(mx, 8, 64));
    mx4[r] = mx;
    need |= (mx - rm[r] > 8.0f) ? 1 : 0;
  }
  if (__any(need)) {
#pragma unroll
    for (int r = 0; r < 4; r++) {
      float mnew = fmaxf(rm[r], mx4[r]);
      float corr = __expf(rm[r] - mnew);
      rs[r] *= corr;
#pragma unroll
      for (int nd = 0; nd < 8; nd++) acco[nd][r] *= corr;
      rm[r] = mnew;
    }
  }
#pragma unroll
  for (int r = 0; r < 4; r++) {
    float psum = 0.f;
#pragma unroll
    for (int n = 0; n < 4; n++) {
      float p = __expf(sacc[n][r] - rm[r]);
      sacc[n][r] = p;
      psum += p;
    }
    rs[r] += psum;                         // per-lane partial; cross-lane reduce at end
  }
#pragma unroll
  for (int n = 0; n < 4; n++)
#pragma unroll
    for (int r = 0; r < 4; r++)
      Psw[lk * 4 + r][n * 16 + lq] = f2bf(sacc[n][r]);
#pragma unroll
  for (int ks2 = 0; ks2 < 2; ks2++) {
    short8 pa = *(const short8*)&Psw[lq][ks2 * 32 + lk * 8];
#pragma unroll
    for (int nd = 0; nd < 8; nd++) {
      short8 vf = *(const short8*)&V0[(nd * 16 + lq) * 64 + ((ks2 * 32 + lk * 8) ^ rsw)];
      acco[nd] = __builtin_amdgcn_mfma_f32_16x16x32_bf16(pa, vf, acco[nd], 0, 0, 0);
    }
  }
}

// ---------------- causal flash attention (merged dual-q-tile sweep) ----------------
__global__ __launch_bounds__(256, 2) void k_attn(
    const unsigned short* __restrict__ qr, const unsigned short* __restrict__ kr,
    const unsigned short* __restrict__ vt, unsigned short* __restrict__ ob) {
  __shared__ unsigned short Kl[2][64 * 128];   // [kv][d] swizzled flat, dbuf
  __shared__ unsigned short Vl[2][128 * 64];   // [d][kv] swizzled flat, dbuf
  __shared__ unsigned short Ps[4][16][72];     // per-wave P round-trip
  int bh = blockIdx.x;
  int yy = blockIdx.y;
  int f = (yy < 8) ? yy : 23 - yy;             // bijective over 0..15
  int qtA = 31 - f, qtB = f;
  int q0A = qtA * 64, q0B = qtB * 64;
  int b = bh >> 4, h = bh & 15;
  int tid = threadIdx.x, lane = tid & 63, w = tid >> 6;
  int lq = lane & 15, lk = lane >> 4;
  const unsigned short* kbh = kr + (size_t)bh * S_LEN * HDIM;
  const unsigned short* vbh = vt + (size_t)bh * HDIM * S_LEN;
  int ksrow = tid >> 4;
  int kscol = ((tid & 15) * 8) ^ ((ksrow & 7) << 3);
  int vsrow = tid >> 3;
  int vscol = ((tid & 7) * 8) ^ ((vsrow & 7) << 3);
  int ldso = tid * 8;
  int rsw = (lq & 7) << 3;

  const unsigned short* qbA =
      qr + ((size_t)bh * S_LEN + q0A + w * 16 + lq) * HDIM + lk * 8;
  const unsigned short* qbB =
      qr + ((size_t)bh * S_LEN + q0B + w * 16 + lq) * HDIM + lk * 8;
  short8 qfA[4], qfB[4];
#pragma unroll
  for (int ks = 0; ks < 4; ks++) {
    qfA[ks] = *(const short8*)(qbA + ks * 32);
    qfB[ks] = *(const short8*)(qbB + ks * 32);
  }

  f32x4 accoA[8], accoB[8];
#pragma unroll
  for (int nd = 0; nd < 8; nd++) {
    accoA[nd][0]=0.f; accoA[nd][1]=0.f; accoA[nd][2]=0.f; accoA[nd][3]=0.f;
    accoB[nd][0]=0.f; accoB[nd][1]=0.f; accoB[nd][2]=0.f; accoB[nd][3]=0.f;
  }
  float rmA[4], rsA[4], rmB[4], rsB[4];
#pragma unroll
  for (int r = 0; r < 4; r++) { rmA[r] = -3.0e38f; rsA[r] = 0.f; rmB[r] = -3.0e38f; rsB[r] = 0.f; }

  // prologue: stage tile 0 into buf 0
#pragma unroll
  for (int c = 0; c < 4; c++) {
    gl_lds16(kbh + (size_t)(c * 16 + ksrow) * HDIM + kscol, &Kl[0][c * 2048 + ldso]);
    gl_lds16(vbh + (size_t)(c * 32 + vsrow) * S_LEN + vscol, &Vl[0][c * 2048 + ldso]);
  }
  __syncthreads();
  int cur = 0;

  for (int t = 0; t <= qtA; t++) {
    int kv0 = t * 64;
    if (t < qtA) {
      int nx = kv0 + 64;
#pragma unroll
      for (int c = 0; c < 4; c++) {
        gl_lds16(kbh + (size_t)(nx + c * 16 + ksrow) * HDIM + kscol,
                 &Kl[cur ^ 1][c * 2048 + ldso]);
        gl_lds16(vbh + (size_t)(c * 32 + vsrow) * S_LEN + nx + vscol,
                 &Vl[cur ^ 1][c * 2048 + ldso]);
      }
    }
    const unsigned short* K0 = &Kl[cur][0];
    const unsigned short* V0 = &Vl[cur][0];
    bool actB = (t <= qtB);

    f32x4 saccA[4], saccB[4];
#pragma unroll
    for (int n = 0; n < 4; n++) {
      saccA[n][0]=0.f; saccA[n][1]=0.f; saccA[n][2]=0.f; saccA[n][3]=0.f;
      saccB[n][0]=0.f; saccB[n][1]=0.f; saccB[n][2]=0.f; saccB[n][3]=0.f;
    }
    if (actB) {
#pragma unroll
      for (int ks = 0; ks < 4; ks++)
#pragma unroll
        for (int n = 0; n < 4; n++) {
          short8 kf = *(const short8*)&K0[(n * 16 + lq) * 128 + ((ks * 32 + lk * 8) ^ rsw)];
          saccA[n] = __builtin_amdgcn_mfma_f32_16x16x32_bf16(qfA[ks], kf, saccA[n], 0, 0, 0);
          saccB[n] = __builtin_amdgcn_mfma_f32_16x16x32_bf16(qfB[ks], kf, saccB[n], 0, 0, 0);
        }
    } else {
#pragma unroll
      for (int ks = 0; ks < 4; ks++)
#pragma unroll
        for (int n = 0; n < 4; n++) {
          short8 kf = *(const short8*)&K0[(n * 16 + lq) * 128 + ((ks * 32 + lk * 8) ^ rsw)];
          saccA[n] = __builtin_amdgcn_mfma_f32_16x16x32_bf16(qfA[ks], kf, saccA[n], 0, 0, 0);
        }
    }
    if (t == qtA) {
#pragma unroll
      for (int n = 0; n < 4; n++)
#pragma unroll
        for (int r = 0; r < 4; r++) {
          int qrow = q0A + w * 16 + lk * 4 + r;
          int kvc = kv0 + n * 16 + lq;
          if (kvc > qrow) saccA[n][r] = -3.0e38f;
        }
    }
    attn_sm_pv(saccA, accoA, rmA, rsA, Ps[w], V0, lq, lk, rsw);
    if (actB) {
      if (t == qtB) {
#pragma unroll
        for (int n = 0; n < 4; n++)
#pragma unroll
          for (int r = 0; r < 4; r++) {
            int qrow = q0B + w * 16 + lk * 4 + r;
            int kvc = kv0 + n * 16 + lq;
            if (kvc > qrow) saccB[n][r] = -3.0e38f;
          }
      }
      attn_sm_pv(saccB, accoB, rmB, rsB, Ps[w], V0, lq, lk, rsw);
    }
    __syncthreads();   // drain next-tile DMA + barrier; buf ready
    cur ^= 1;
  }

  // final cross-lane sum reduce (deferred), then normalize + store
#pragma unroll
  for (int r = 0; r < 4; r++) {
    float sA = rsA[r];
    sA += __shfl_xor(sA, 1, 64);
    sA += __shfl_xor(sA, 2, 64);
    sA += __shfl_xor(sA, 4, 64);
    sA += __shfl_xor(sA, 8, 64);
    float invA = 1.0f / sA;
    int srowA = q0A + w * 16 + lk * 4 + r;
    unsigned short* dstA = ob + ((size_t)b * S_LEN + srowA) * DMODEL + h * HDIM;
#pragma unroll
    for (int nd = 0; nd < 8; nd++) dstA[nd * 16 + lq] = f2bf(accoA[nd][r] * invA);
    float sB = rsB[r];
    sB += __shfl_xor(sB, 1, 64);
    sB += __shfl_xor(sB, 2, 64);
    sB += __shfl_xor(sB, 4, 64);
    sB += __shfl_xor(sB, 8, 64);
    float invB = 1.0f / sB;
    int srowB = q0B + w * 16 + lk * 4 + r;
    unsigned short* dstB = ob + ((size_t)b * S_LEN + srowB) * DMODEL + h * HDIM;
#pragma unroll
    for (int nd = 0; nd < 8; nd++) dstB[nd * 16 + lq] = f2bf(accoB[nd][r] * invB);
  }
}

extern "C" void kernel_launch(void* const* d_in, const int* in_sizes, int n_in,
                              void* d_out, int out_size, void* d_ws, size_t ws_size,
                              hipStream_t stream) {
  const float* x  = (const float*)d_in[0];
  const float* Wq = (const float*)d_in[2];
  const float* bq = (const float*)d_in[3];
  const float* Wk = (const float*)d_in[4];
  const float* bk = (const float*)d_in[5];
  const float* Wv = (const float*)d_in[6];
  const float* bv = (const float*)d_in[7];
  const float* Wo = (const float*)d_in[8];
  const float* bo = (const float*)d_in[9];
  float* out = (float*)d_out;
  char* ws = (char*)d_ws;

  unsigned short* xb  = (unsigned short*)(ws + XB_OFF);
  unsigned short* wqb = (unsigned short*)(ws + WQ_OFF);
  unsigned short* wkb = (unsigned short*)(ws + WK_OFF);
  unsigned short* wvb = (unsigned short*)(ws + WV_OFF);
  unsigned short* qr  = (unsigned short*)(ws + Q_OFF);
  unsigned short* kr  = (unsigned short*)(ws + K_OFF);
  unsigned short* vt  = (unsigned short*)(ws + VT_OFF);
  float* ct = (float*)(ws + COS_OFF);
  float* st = (float*)(ws + SIN_OFF);
  bool haveWo = (ws_size >= WS_NEED);
  unsigned short* wob = haveWo ? (unsigned short*)(ws + WO_OFF) : nullptr;

  // x + Wq/Wk/Wv (+Wo if slot fits) converts + rope table, one launch
  k_prep<<<25088, 256, 0, stream>>>(x, Wq, Wk, Wv, Wo, xb, wqb, wkb, wvb, wob, ct, st);
  // fused QKV projection + RoPE + layout transform (Q scaled by 1/sqrt(128))
  k_gemm_qkv<<<dim3(MROWS / 128, 6144 / 128), 256, 0, stream>>>(
      xb, wqb, wkb, wvb, bq, bk, bv, ct, st, qr, kr, vt);
  if (!haveWo)
    k_cvt<<<(DMODEL * DMODEL / 4 + 255) / 256, 256, 0, stream>>>(Wo, wqb, DMODEL * DMODEL / 4);
  k_attn<<<dim3(BHTOT, 16), 256, 0, stream>>>(qr, kr, vt, xb);
  k_gemm_out<<<dim3(MROWS / 128, DMODEL / 128), 256, 0, stream>>>(
      xb, haveWo ? wob : wqb, bo, out);
}

// Round 11
// 232.150 us; speedup vs baseline: 2.1680x; 2.1680x over previous
//
#include <hip/hip_runtime.h>
#include <stdint.h>
#include <math.h>

typedef short short8 __attribute__((ext_vector_type(8)));
typedef float f32x4 __attribute__((ext_vector_type(4)));

// Problem constants
#define S_LEN   2048
#define DMODEL  2048
#define NHEADS  16
#define HDIM    128
#define NBATCH  2
#define BHTOT   32      // NBATCH*NHEADS
#define MROWS   4096    // NBATCH*S_LEN

// Workspace byte offsets
#define XB_OFF   ((size_t)0)          // x bf16; reused as attn-output O
#define WQ_OFF   ((size_t)16777216)   // Wq bf16; reused for Wo bf16 (fallback path)
#define WK_OFF   ((size_t)25165824)
#define WV_OFF   ((size_t)33554432)
#define Q_OFF    ((size_t)41943040)   // (bh,s,d) bf16
#define K_OFF    ((size_t)58720256)   // (bh,s,d) bf16
#define VT_OFF   ((size_t)75497472)   // (bh,d,s) bf16 (V pre-transposed)
#define COS_OFF  ((size_t)92274688)   // 2048*64 f32
#define SIN_OFF  ((size_t)92798976)   // 2048*64 f32
#define WO_OFF   ((size_t)93323264)   // dedicated Wo bf16 slot (if ws_size permits)
#define WS_NEED  (WO_OFF + (size_t)8388608)

__device__ __forceinline__ unsigned short f2bf(float f) {
  unsigned int u = __float_as_uint(f);
  unsigned int r = (u + 0x7FFFu + ((u >> 16) & 1u)) >> 16;  // RTNE
  return (unsigned short)r;
}
__device__ __forceinline__ float bf2f(unsigned short b) {
  return __uint_as_float(((unsigned int)b) << 16);
}

// async global->LDS, 16B per lane; LDS dest = wave-uniform base + lane*16
__device__ __forceinline__ void gl_lds16(const unsigned short* g, unsigned short* l) {
  __builtin_amdgcn_global_load_lds(
      (const __attribute__((address_space(1))) unsigned int*)(g),
      (__attribute__((address_space(3))) unsigned int*)(l),
      16, 0, 0);
}

// ---------------- fp32 -> bf16 convert (fallback for Wo) ----------------
__global__ __launch_bounds__(256) void k_cvt(const float* __restrict__ src,
                                             unsigned short* __restrict__ dst, int n4) {
  int i = blockIdx.x * 256 + threadIdx.x;
  if (i >= n4) return;
  float4 v = ((const float4*)src)[i];
  ushort4 o;
  o.x = f2bf(v.x); o.y = f2bf(v.y); o.z = f2bf(v.z); o.w = f2bf(v.w);
  ((ushort4*)dst)[i] = o;
}

// ---------------- merged prep: x->bf16, Wq/Wk/Wv(/Wo)->bf16, RoPE table ----------------
__global__ __launch_bounds__(256) void k_prep(
    const float* __restrict__ x, const float* __restrict__ Wq,
    const float* __restrict__ Wk, const float* __restrict__ Wv,
    const float* __restrict__ Wo,
    unsigned short* __restrict__ xb, unsigned short* __restrict__ wqb,
    unsigned short* __restrict__ wkb, unsigned short* __restrict__ wvb,
    unsigned short* __restrict__ wob,   // null if no dedicated slot
    float* __restrict__ ct, float* __restrict__ st) {
  int i = blockIdx.x * 256 + threadIdx.x;
  if (i < 6291456) {                       // float4 converts: x (2^21) + 4 W (2^20 each)
    const float* s; unsigned short* d; int off;
    if (i < 2097152) { s = x; d = xb; off = i; }
    else {
      int j = i - 2097152, sel = j >> 20;
      off = j & 1048575;
      if (sel == 3) {
        if (!wob) return;                  // fallback: separate k_cvt handles Wo
        s = Wo; d = wob;
      } else {
        s = (sel == 0) ? Wq : (sel == 1 ? Wk : Wv);
        d = (sel == 0) ? wqb : (sel == 1 ? wkb : wvb);
      }
    }
    float4 v = ((const float4*)s)[off];
    ushort4 o;
    o.x = f2bf(v.x); o.y = f2bf(v.y); o.z = f2bf(v.z); o.w = f2bf(v.w);
    ((ushort4*)d)[off] = o;
  } else {
    int j = i - 6291456;                   // 2048*64 rope table entries
    if (j < S_LEN * 64) {
      int s = j >> 6, jj = j & 63;
      float inv = expf(-(float)(2 * jj) * (9.210340371976184f / 128.0f));
      float ang = (float)s * inv;
      ct[j] = cosf(ang);
      st[j] = sinf(ang);
    }
  }
}

// ---------------- fused QKV projection GEMM + RoPE + transpose epilogue ----------------
// T3 minimum-2-phase: double-buffered global_load_lds staging (issue next K-tile's
// DMA before computing current; ONE barrier per K-step). LDS 64 KB -> 2 blocks/CU,
// equal to the register cap (104 VGPR + 64 AGPR), so no occupancy loss.
// [r10 lesson: A-direct-to-reg regressed 3x — occupancy step (168->196 regs) +
//  exposed scatter latency; LDS->MFMA is already hidden by compiler lgkmcnt.]
#define CP 136
__global__ __launch_bounds__(256) void k_gemm_qkv(
    const unsigned short* __restrict__ xb,
    const unsigned short* __restrict__ wqb, const unsigned short* __restrict__ wkb,
    const unsigned short* __restrict__ wvb,
    const float* __restrict__ bq, const float* __restrict__ bk, const float* __restrict__ bv,
    const float* __restrict__ ct, const float* __restrict__ st,
    unsigned short* __restrict__ qr, unsigned short* __restrict__ kr,
    unsigned short* __restrict__ vt) {
  __shared__ unsigned short SMEM[32768];   // 64 KB: buf0 A[0,8192) B[8192,16384); buf1 +16384
  int m0 = blockIdx.x * 128;
  int n0g = blockIdx.y * 128;              // 0..6143
  int wsel = n0g >> 11;                    // 0=Q 1=K 2=V
  int nw0 = n0g & (DMODEL - 1);
  const unsigned short* W = (wsel == 0) ? wqb : (wsel == 1 ? wkb : wvb);
  const float* bias = (wsel == 0) ? bq : (wsel == 1 ? bk : bv);
  int tid = threadIdx.x, lane = tid & 63, wid = tid >> 6;
  int wr = wid >> 1, wc = wid & 1;
  int lq = lane & 15, lk = lane >> 4;
  int gr = wid * 32 + (lane >> 3);                       // staging row (i=0)
  int gc = ((lane & 7) * 8) ^ ((lane >> 3) << 3);        // pre-swizzled source col
  int lbase = (wid * 32) * 64;                           // wave-uniform LDS elem offset

  f32x4 acc[4][4];
#pragma unroll
  for (int m = 0; m < 4; m++)
#pragma unroll
    for (int n = 0; n < 4; n++) { acc[m][n][0]=0.f; acc[m][n][1]=0.f; acc[m][n][2]=0.f; acc[m][n][3]=0.f; }

  // prologue: stage K-tile 0 into buf 0
#pragma unroll
  for (int i = 0; i < 4; i++) {
    gl_lds16(xb + (size_t)(m0 + gr + i * 8) * DMODEL + gc, SMEM + lbase + i * 512);
    gl_lds16(W  + (size_t)(nw0 + gr + i * 8) * DMODEL + gc, SMEM + 8192 + lbase + i * 512);
  }
  __syncthreads();
  int cur = 0;

  for (int k0 = 0; k0 < DMODEL; k0 += 64) {
    // issue next tile's DMA into buf^1 (in flight across this tile's compute)
    if (k0 + 64 < DMODEL) {
      int kn = k0 + 64;
      unsigned short* An = SMEM + (cur ^ 1) * 16384;
#pragma unroll
      for (int i = 0; i < 4; i++) {
        gl_lds16(xb + (size_t)(m0 + gr + i * 8) * DMODEL + kn + gc, An + lbase + i * 512);
        gl_lds16(W  + (size_t)(nw0 + gr + i * 8) * DMODEL + kn + gc, An + 8192 + lbase + i * 512);
      }
    }
    const unsigned short* Ac = SMEM + cur * 16384;
    const unsigned short* Bc = Ac + 8192;
#pragma unroll
    for (int kk = 0; kk < 2; kk++) {
      short8 af[4], bfr[4];
      int sw = (lq & 7) << 3;
#pragma unroll
      for (int m = 0; m < 4; m++)
        af[m] = *(const short8*)&Ac[(wr * 64 + m * 16 + lq) * 64 + ((kk * 32 + lk * 8) ^ sw)];
#pragma unroll
      for (int n = 0; n < 4; n++)
        bfr[n] = *(const short8*)&Bc[(wc * 64 + n * 16 + lq) * 64 + ((kk * 32 + lk * 8) ^ sw)];
#pragma unroll
      for (int m = 0; m < 4; m++)
#pragma unroll
        for (int n = 0; n < 4; n++)
          acc[m][n] = __builtin_amdgcn_mfma_f32_16x16x32_bf16(af[m], bfr[n], acc[m][n], 0, 0, 0);
    }
    __syncthreads();   // drain next-tile DMA + all reads of buf[cur] done
    cur ^= 1;
  }

  // ---- epilogue: bias (+RoPE for Q/K) -> SMEM[0,17408) in target layout -> coalesced store
  int h = nw0 >> 7, b = m0 >> 11, s0 = m0 & (S_LEN - 1);
  float bi[4];
#pragma unroll
  for (int n = 0; n < 4; n++) bi[n] = bias[nw0 + wc * 64 + n * 16 + lq];

  if (wsel < 2) {
    float qs = (wsel == 0) ? 0.08838834764831843f : 1.0f;
    if (wc == 0) {
#pragma unroll
      for (int m = 0; m < 4; m++) {
        int sl = wr * 64 + m * 16 + lk * 4;
#pragma unroll
        for (int r = 0; r < 4; r++) {
          int s = (s0 + sl + r);
          const float* cb = ct + s * 64;
          const float* sb = st + s * 64;
#pragma unroll
          for (int n = 0; n < 2; n++) {
            int fq = n * 16 + lq;
            float x1 = acc[m][n][r] + bi[n];
            float x2 = acc[m][n + 2][r] + bi[n + 2];
            SMEM[(sl + r) * CP + fq]      = f2bf((x1 * cb[fq]      - x2 * sb[fq])      * qs);
            SMEM[(sl + r) * CP + fq + 32] = f2bf((x2 * cb[fq + 32] + x1 * sb[fq + 32]) * qs);
          }
        }
      }
    } else {
#pragma unroll
      for (int m = 0; m < 4; m++) {
        int sl = wr * 64 + m * 16 + lk * 4;
#pragma unroll
        for (int n = 0; n < 4; n++) {
          int fq = 64 + n * 16 + lq;
#pragma unroll
          for (int r = 0; r < 4; r++)
            SMEM[(sl + r) * CP + fq] = f2bf((acc[m][n][r] + bi[n]) * qs);
        }
      }
    }
    __syncthreads();
    int row = tid >> 1, hf2 = tid & 1;
    unsigned short* dstb = (wsel == 0 ? qr : kr) +
        ((size_t)(b * NHEADS + h) * S_LEN + s0 + row) * HDIM + hf2 * 64;
    const unsigned short* srcb = &SMEM[row * CP + hf2 * 64];
#pragma unroll
    for (int j = 0; j < 8; j++)
      *(short8*)(dstb + j * 8) = *(const short8*)(srcb + j * 8);
  } else {
#pragma unroll
    for (int m = 0; m < 4; m++) {
      int sl = wr * 64 + m * 16 + lk * 4;
#pragma unroll
      for (int n = 0; n < 4; n++) {
        int fq = wc * 64 + n * 16 + lq;
#pragma unroll
        for (int r = 0; r < 4; r++)
          SMEM[fq * CP + sl + r] = f2bf(acc[m][n][r] + bi[n]);
      }
    }
    __syncthreads();
    int row = tid >> 1, hf2 = tid & 1;
    unsigned short* dstb = vt +
        ((size_t)(b * NHEADS + h) * HDIM + row) * S_LEN + s0 + hf2 * 64;
    const unsigned short* srcb = &SMEM[row * CP + hf2 * 64];
#pragma unroll
    for (int j = 0; j < 8; j++)
      *(short8*)(dstb + j * 8) = *(const short8*)(srcb + j * 8);
  }
}

// ---------------- attn per-tile softmax (defer-max, per-lane partial sums) ----------------
__device__ __forceinline__ void attn_sm_pv(
    f32x4* sacc, f32x4* acco, float* rm, float* rs,
    unsigned short (*Psw)[72], const unsigned short* V0,
    int lq, int lk, int rsw) {
  float mx4[4];
  int need = 0;
#pragma unroll
  for (int r = 0; r < 4; r++) {
    float mx = fmaxf(fmaxf(sacc[0][r], sacc[1][r]), fmaxf(sacc[2][r], sacc[3][r]));
    mx = fmaxf(mx, __shfl_xor(mx, 1, 64));
    mx = fmaxf(mx, __shfl_xor(mx, 2, 64));
    mx = fmaxf(mx, __shfl_xor(mx, 4, 64));
    mx = fmaxf(mx, __shfl_xor(mx, 8, 64));
    mx4[r] = mx;
    need |= (mx - rm[r] > 8.0f) ? 1 : 0;
  }
  if (__any(need)) {
#pragma unroll
    for (int r = 0; r < 4; r++) {
      float mnew = fmaxf(rm[r], mx4[r]);
      float corr = __expf(rm[r] - mnew);
      rs[r] *= corr;
#pragma unroll
      for (int nd = 0; nd < 8; nd++) acco[nd][r] *= corr;
      rm[r] = mnew;
    }
  }
#pragma unroll
  for (int r = 0; r < 4; r++) {
    float psum = 0.f;
#pragma unroll
    for (int n = 0; n < 4; n++) {
      float p = __expf(sacc[n][r] - rm[r]);
      sacc[n][r] = p;
      psum += p;
    }
    rs[r] += psum;                         // per-lane partial; cross-lane reduce at end
  }
#pragma unroll
  for (int n = 0; n < 4; n++)
#pragma unroll
    for (int r = 0; r < 4; r++)
      Psw[lk * 4 + r][n * 16 + lq] = f2bf(sacc[n][r]);
#pragma unroll
  for (int ks2 = 0; ks2 < 2; ks2++) {
    short8 pa = *(const short8*)&Psw[lq][ks2 * 32 + lk * 8];
#pragma unroll
    for (int nd = 0; nd < 8; nd++) {
      short8 vf = *(const short8*)&V0[(nd * 16 + lq) * 64 + ((ks2 * 32 + lk * 8) ^ rsw)];
      acco[nd] = __builtin_amdgcn_mfma_f32_16x16x32_bf16(pa, vf, acco[nd], 0, 0, 0);
    }
  }
}

// ---------------- causal flash attention (merged dual-q-tile sweep) ----------------
__global__ __launch_bounds__(256, 2) void k_attn(
    const unsigned short* __restrict__ qr, const unsigned short* __restrict__ kr,
    const unsigned short* __restrict__ vt, unsigned short* __restrict__ ob) {
  __shared__ unsigned short Kl[2][64 * 128];   // [kv][d] swizzled flat, dbuf
  __shared__ unsigned short Vl[2][128 * 64];   // [d][kv] swizzled flat, dbuf
  __shared__ unsigned short Ps[4][16][72];     // per-wave P round-trip
  int bh = blockIdx.x;
  int yy = blockIdx.y;
  int f = (yy < 8) ? yy : 23 - yy;             // bijective over 0..15
  int qtA = 31 - f, qtB = f;
  int q0A = qtA * 64, q0B = qtB * 64;
  int b = bh >> 4, h = bh & 15;
  int tid = threadIdx.x, lane = tid & 63, w = tid >> 6;
  int lq = lane & 15, lk = lane >> 4;
  const unsigned short* kbh = kr + (size_t)bh * S_LEN * HDIM;
  const unsigned short* vbh = vt + (size_t)bh * HDIM * S_LEN;
  int ksrow = tid >> 4;
  int kscol = ((tid & 15) * 8) ^ ((ksrow & 7) << 3);
  int vsrow = tid >> 3;
  int vscol = ((tid & 7) * 8) ^ ((vsrow & 7) << 3);
  int ldso = tid * 8;
  int rsw = (lq & 7) << 3;

  const unsigned short* qbA =
      qr + ((size_t)bh * S_LEN + q0A + w * 16 + lq) * HDIM + lk * 8;
  const unsigned short* qbB =
      qr + ((size_t)bh * S_LEN + q0B + w * 16 + lq) * HDIM + lk * 8;
  short8 qfA[4], qfB[4];
#pragma unroll
  for (int ks = 0; ks < 4; ks++) {
    qfA[ks] = *(const short8*)(qbA + ks * 32);
    qfB[ks] = *(const short8*)(qbB + ks * 32);
  }

  f32x4 accoA[8], accoB[8];
#pragma unroll
  for (int nd = 0; nd < 8; nd++) {
    accoA[nd][0]=0.f; accoA[nd][1]=0.f; accoA[nd][2]=0.f; accoA[nd][3]=0.f;
    accoB[nd][0]=0.f; accoB[nd][1]=0.f; accoB[nd][2]=0.f; accoB[nd][3]=0.f;
  }
  float rmA[4], rsA[4], rmB[4], rsB[4];
#pragma unroll
  for (int r = 0; r < 4; r++) { rmA[r] = -3.0e38f; rsA[r] = 0.f; rmB[r] = -3.0e38f; rsB[r] = 0.f; }

  // prologue: stage tile 0 into buf 0
#pragma unroll
  for (int c = 0; c < 4; c++) {
    gl_lds16(kbh + (size_t)(c * 16 + ksrow) * HDIM + kscol, &Kl[0][c * 2048 + ldso]);
    gl_lds16(vbh + (size_t)(c * 32 + vsrow) * S_LEN + vscol, &Vl[0][c * 2048 + ldso]);
  }
  __syncthreads();
  int cur = 0;

  for (int t = 0; t <= qtA; t++) {
    int kv0 = t * 64;
    if (t < qtA) {
      int nx = kv0 + 64;
#pragma unroll
      for (int c = 0; c < 4; c++) {
        gl_lds16(kbh + (size_t)(nx + c * 16 + ksrow) * HDIM + kscol,
                 &Kl[cur ^ 1][c * 2048 + ldso]);
        gl_lds16(vbh + (size_t)(c * 32 + vsrow) * S_LEN + nx + vscol,
                 &Vl[cur ^ 1][c * 2048 + ldso]);
      }
    }
    const unsigned short* K0 = &Kl[cur][0];
    const unsigned short* V0 = &Vl[cur][0];
    bool actB = (t <= qtB);

    f32x4 saccA[4], saccB[4];
#pragma unroll
    for (int n = 0; n < 4; n++) {
      saccA[n][0]=0.f; saccA[n][1]=0.f; saccA[n][2]=0.f; saccA[n][3]=0.f;
      saccB[n][0]=0.f; saccB[n][1]=0.f; saccB[n][2]=0.f; saccB[n][3]=0.f;
    }
    if (actB) {
#pragma unroll
      for (int ks = 0; ks < 4; ks++)
#pragma unroll
        for (int n = 0; n < 4; n++) {
          short8 kf = *(const short8*)&K0[(n * 16 + lq) * 128 + ((ks * 32 + lk * 8) ^ rsw)];
          saccA[n] = __builtin_amdgcn_mfma_f32_16x16x32_bf16(qfA[ks], kf, saccA[n], 0, 0, 0);
          saccB[n] = __builtin_amdgcn_mfma_f32_16x16x32_bf16(qfB[ks], kf, saccB[n], 0, 0, 0);
        }
    } else {
#pragma unroll
      for (int ks = 0; ks < 4; ks++)
#pragma unroll
        for (int n = 0; n < 4; n++) {
          short8 kf = *(const short8*)&K0[(n * 16 + lq) * 128 + ((ks * 32 + lk * 8) ^ rsw)];
          saccA[n] = __builtin_amdgcn_mfma_f32_16x16x32_bf16(qfA[ks], kf, saccA[n], 0, 0, 0);
        }
    }
    if (t == qtA) {
#pragma unroll
      for (int n = 0; n < 4; n++)
#pragma unroll
        for (int r = 0; r < 4; r++) {
          int qrow = q0A + w * 16 + lk * 4 + r;
          int kvc = kv0 + n * 16 + lq;
          if (kvc > qrow) saccA[n][r] = -3.0e38f;
        }
    }
    attn_sm_pv(saccA, accoA, rmA, rsA, Ps[w], V0, lq, lk, rsw);
    if (actB) {
      if (t == qtB) {
#pragma unroll
        for (int n = 0; n < 4; n++)
#pragma unroll
          for (int r = 0; r < 4; r++) {
            int qrow = q0B + w * 16 + lk * 4 + r;
            int kvc = kv0 + n * 16 + lq;
            if (kvc > qrow) saccB[n][r] = -3.0e38f;
          }
      }
      attn_sm_pv(saccB, accoB, rmB, rsB, Ps[w], V0, lq, lk, rsw);
    }
    __syncthreads();   // drain next-tile DMA + barrier; buf ready
    cur ^= 1;
  }

  // final cross-lane sum reduce (deferred), then normalize + store
#pragma unroll
  for (int r = 0; r < 4; r++) {
    float sA = rsA[r];
    sA += __shfl_xor(sA, 1, 64);
    sA += __shfl_xor(sA, 2, 64);
    sA += __shfl_xor(sA, 4, 64);
    sA += __shfl_xor(sA, 8, 64);
    float invA = 1.0f / sA;
    int srowA = q0A + w * 16 + lk * 4 + r;
    unsigned short* dstA = ob + ((size_t)b * S_LEN + srowA) * DMODEL + h * HDIM;
#pragma unroll
    for (int nd = 0; nd < 8; nd++) dstA[nd * 16 + lq] = f2bf(accoA[nd][r] * invA);
    float sB = rsB[r];
    sB += __shfl_xor(sB, 1, 64);
    sB += __shfl_xor(sB, 2, 64);
    sB += __shfl_xor(sB, 4, 64);
    sB += __shfl_xor(sB, 8, 64);
    float invB = 1.0f / sB;
    int srowB = q0B + w * 16 + lk * 4 + r;
    unsigned short* dstB = ob + ((size_t)b * S_LEN + srowB) * DMODEL + h * HDIM;
#pragma unroll
    for (int nd = 0; nd < 8; nd++) dstB[nd * 16 + lq] = f2bf(accoB[nd][r] * invB);
  }
}

// ---------------- output projection GEMM (T3 2-phase dbuf, fp32 out) ----------------
__global__ __launch_bounds__(256) void k_gemm_out(
    const unsigned short* __restrict__ ob, const unsigned short* __restrict__ wob,
    const float* __restrict__ bo, float* __restrict__ out) {
  __shared__ unsigned short SMEM[32768];   // 64 KB dbuf
  int m0 = blockIdx.x * 128, n0 = blockIdx.y * 128;
  int tid = threadIdx.x, lane = tid & 63, wid = tid >> 6;
  int wr = wid >> 1, wc = wid & 1;
  int lq = lane & 15, lk = lane >> 4;
  int gr = wid * 32 + (lane >> 3);
  int gc = ((lane & 7) * 8) ^ ((lane >> 3) << 3);
  int lbase = (wid * 32) * 64;

  f32x4 acc[4][4];
#pragma unroll
  for (int m = 0; m < 4; m++)
#pragma unroll
    for (int n = 0; n < 4; n++) { acc[m][n][0]=0.f; acc[m][n][1]=0.f; acc[m][n][2]=0.f; acc[m][n][3]=0.f; }

  // prologue: stage K-tile 0 into buf 0
#pragma unroll
  for (int i = 0; i < 4; i++) {
    gl_lds16(ob  + (size_t)(m0 + gr + i * 8) * DMODEL + gc, SMEM + lbase + i * 512);
    gl_lds16(wob + (size_t)(n0 + gr + i * 8) * DMODEL + gc, SMEM + 8192 + lbase + i * 512);
  }
  __syncthreads();
  int cur = 0;

  for (int k0 = 0; k0 < DMODEL; k0 += 64) {
    if (k0 + 64 < DMODEL) {
      int kn = k0 + 64;
      unsigned short* An = SMEM + (cur ^ 1) * 16384;
#pragma unroll
      for (int i = 0; i < 4; i++) {
        gl_lds16(ob  + (size_t)(m0 + gr + i * 8) * DMODEL + kn + gc, An + lbase + i * 512);
        gl_lds16(wob + (size_t)(n0 + gr + i * 8) * DMODEL + kn + gc, An + 8192 + lbase + i * 512);
      }
    }
    const unsigned short* Ac = SMEM + cur * 16384;
    const unsigned short* Bc = Ac + 8192;
#pragma unroll
    for (int kk = 0; kk < 2; kk++) {
      short8 af[4], bfr[4];
      int sw = (lq & 7) << 3;
#pragma unroll
      for (int m = 0; m < 4; m++)
        af[m] = *(const short8*)&Ac[(wr * 64 + m * 16 + lq) * 64 + ((kk * 32 + lk * 8) ^ sw)];
#pragma unroll
      for (int n = 0; n < 4; n++)
        bfr[n] = *(const short8*)&Bc[(wc * 64 + n * 16 + lq) * 64 + ((kk * 32 + lk * 8) ^ sw)];
#pragma unroll
      for (int m = 0; m < 4; m++)
#pragma unroll
        for (int n = 0; n < 4; n++)
          acc[m][n] = __builtin_amdgcn_mfma_f32_16x16x32_bf16(af[m], bfr[n], acc[m][n], 0, 0, 0);
    }
    __syncthreads();
    cur ^= 1;
  }
#pragma unroll
  for (int n = 0; n < 4; n++) {
    int el = n0 + wc * 64 + n * 16 + lq;
    float bi = bo[el];
#pragma unroll
    for (int m = 0; m < 4; m++) {
      int row = m0 + wr * 64 + m * 16 + lk * 4;
#pragma unroll
      for (int r = 0; r < 4; r++)
        out[(size_t)(row + r) * DMODEL + el] = acc[m][n][r] + bi;
    }
  }
}

extern "C" void kernel_launch(void* const* d_in, const int* in_sizes, int n_in,
                              void* d_out, int out_size, void* d_ws, size_t ws_size,
                              hipStream_t stream) {
  const float* x  = (const float*)d_in[0];
  const float* Wq = (const float*)d_in[2];
  const float* bq = (const float*)d_in[3];
  const float* Wk = (const float*)d_in[4];
  const float* bk = (const float*)d_in[5];
  const float* Wv = (const float*)d_in[6];
  const float* bv = (const float*)d_in[7];
  const float* Wo = (const float*)d_in[8];
  const float* bo = (const float*)d_in[9];
  float* out = (float*)d_out;
  char* ws = (char*)d_ws;

  unsigned short* xb  = (unsigned short*)(ws + XB_OFF);
  unsigned short* wqb = (unsigned short*)(ws + WQ_OFF);
  unsigned short* wkb = (unsigned short*)(ws + WK_OFF);
  unsigned short* wvb = (unsigned short*)(ws + WV_OFF);
  unsigned short* qr  = (unsigned short*)(ws + Q_OFF);
  unsigned short* kr  = (unsigned short*)(ws + K_OFF);
  unsigned short* vt  = (unsigned short*)(ws + VT_OFF);
  float* ct = (float*)(ws + COS_OFF);
  float* st = (float*)(ws + SIN_OFF);
  bool haveWo = (ws_size >= WS_NEED);
  unsigned short* wob = haveWo ? (unsigned short*)(ws + WO_OFF) : nullptr;

  // x + Wq/Wk/Wv (+Wo if slot fits) converts + rope table, one launch
  k_prep<<<25088, 256, 0, stream>>>(x, Wq, Wk, Wv, Wo, xb, wqb, wkb, wvb, wob, ct, st);
  // fused QKV projection + RoPE + layout transform (Q scaled by 1/sqrt(128))
  k_gemm_qkv<<<dim3(MROWS / 128, 6144 / 128), 256, 0, stream>>>(
      xb, wqb, wkb, wvb, bq, bk, bv, ct, st, qr, kr, vt);
  if (!haveWo)
    k_cvt<<<(DMODEL * DMODEL / 4 + 255) / 256, 256, 0, stream>>>(Wo, wqb, DMODEL * DMODEL / 4);
  k_attn<<<dim3(BHTOT, 16), 256, 0, stream>>>(qr, kr, vt, xb);
  k_gemm_out<<<dim3(MROWS / 128, DMODEL / 128), 256, 0, stream>>>(
      xb, haveWo ? wob : wqb, bo, out);
}